// Round 6
// baseline (186.043 us; speedup 1.0000x reference)
//
#include <hip/hip_runtime.h>
#include <math.h>

#ifndef M_PI
#define M_PI 3.14159265358979323846
#endif

typedef float v4f __attribute__((ext_vector_type(4)));

constexpr int BLOCK = 256;   // one i-point per lane
constexpr int SPLIT = 32;    // j-dimension slices (blockIdx.y)

// y[i,c] = norms[c] * sum_j exp(-(a[j] + b[i,c]) * ||xi-xj||^2) * f[j]
// b[i,:] = {a[i]/2, a[i], 2a[i]}  (B0=B2, C0=C2 when A=D=2)
// u = exp2(-(a_i/2)L*s), A = exp2(-a_j*L*s)  ->  w = {A*u, A*u^2, A*u^4}
// s = (q_j + q_i) - 2*xj.xi,  q = |x|^2
//
// NO inline asm (R3-R5 all failed catastrophically with hand-written
// v_pk_*_f32). Plain <4 x float> C arithmetic on per-lane VGPR data; the
// backend may legally form v_pk_*_f32 itself (hasPackedFP32Ops). j-data is
// loaded with per-lane float4 loads (runtime-uniform address -> broadcast).

// SoA precompute: X,Y,Z,Q,An,F  (An = -a_j*log2e, Q = |x|^2, F = w*rho)
__global__ __launch_bounds__(256)
void cider_pre(const float* __restrict__ rho, const float* __restrict__ gamma,
               const float* __restrict__ coords, const float* __restrict__ weights,
               float* __restrict__ X, float* __restrict__ Y,
               float* __restrict__ Z, float* __restrict__ Q,
               float* __restrict__ An, float* __restrict__ F,
               int n, float C2, float Kttf)
{
    int j = blockIdx.x * 256 + threadIdx.x;
    if (j >= n) return;
    const float LOG2E = 1.4426950408889634f;
    const float PI_F  = 3.14159265358979f;
    float r  = rho[j] + 1e-8f;
    float sc = PI_F * powf(0.5f * r, 2.0f / 3.0f);
    float xq = (gamma[j] / (8.0f * r)) / (Kttf * powf(r, 5.0f / 3.0f));
    float x = coords[3*j], y = coords[3*j+1], z = coords[3*j+2];
    An[j] = -(LOG2E * sc * (2.0f + C2 * xq));
    X[j]  = x;  Y[j] = y;  Z[j] = z;
    Q[j]  = x*x + y*y + z*z;
    F[j]  = weights[j] * rho[j];
}

__global__ __launch_bounds__(BLOCK)
void cider_main(const float* __restrict__ X, const float* __restrict__ Y,
                const float* __restrict__ Z, const float* __restrict__ Q,
                const float* __restrict__ An, const float* __restrict__ F,
                float* __restrict__ out,
                int n, int zero, float n1, float n2, float n3)
{
    const int i      = blockIdx.x * BLOCK + threadIdx.x;
    const int jcount = n / SPLIT;
    const int j0     = blockIdx.y * jcount;

    const float xi = X[i], yi = Y[i], zi = Z[i], qi = Q[i];
    const float m2s = 0.5f * An[i];          // -(a_i/2)*log2e

    const v4f mx2 = {-2.0f*xi, -2.0f*xi, -2.0f*xi, -2.0f*xi};
    const v4f my2 = {-2.0f*yi, -2.0f*yi, -2.0f*yi, -2.0f*yi};
    const v4f mz2 = {-2.0f*zi, -2.0f*zi, -2.0f*zi, -2.0f*zi};
    const v4f qi4 = {qi, qi, qi, qi};
    const v4f m2n = {m2s, m2s, m2s, m2s};

    // per-lane vector loads: runtime-zero lane term defeats scalarization
    const int base = j0 + zero * (int)threadIdx.x;
    const v4f* __restrict__ Xp = (const v4f*)(X  + base);
    const v4f* __restrict__ Yp = (const v4f*)(Y  + base);
    const v4f* __restrict__ Zp = (const v4f*)(Z  + base);
    const v4f* __restrict__ Qp = (const v4f*)(Q  + base);
    const v4f* __restrict__ Ap = (const v4f*)(An + base);
    const v4f* __restrict__ Fp = (const v4f*)(F  + base);

    v4f acc1 = {0.f,0.f,0.f,0.f}, acc2 = acc1, acc3 = acc1;

    const int nt = jcount / 4;
    #pragma unroll 2
    for (int t = 0; t < nt; ++t) {
        v4f XX = Xp[t], YY = Yp[t], ZZ = Zp[t];
        v4f QQ = Qp[t], AA = Ap[t], FF = Fp[t];

        v4f s = QQ + qi4;                 // q_j + q_i
        s = XX * mx2 + s;                 // fma: -2 xj xi
        s = YY * my2 + s;
        s = ZZ * mz2 + s;
        v4f argA = AA  * s;               // -a_j L s
        v4f argU = m2n * s;               // -(a_i/2) L s
        v4f A, u;
        A.x = __builtin_amdgcn_exp2f(argA.x);
        A.y = __builtin_amdgcn_exp2f(argA.y);
        A.z = __builtin_amdgcn_exp2f(argA.z);
        A.w = __builtin_amdgcn_exp2f(argA.w);
        u.x = __builtin_amdgcn_exp2f(argU.x);
        u.y = __builtin_amdgcn_exp2f(argU.y);
        u.z = __builtin_amdgcn_exp2f(argU.z);
        u.w = __builtin_amdgcn_exp2f(argU.w);
        v4f u2 = u * u;
        v4f u4 = u2 * u2;
        v4f t0 = FF * A;                  // A * f_j
        acc1 = t0 * u  + acc1;
        acc2 = t0 * u2 + acc2;
        acc3 = t0 * u4 + acc3;
    }

    atomicAdd(&out[3*i+0], (acc1.x + acc1.y + acc1.z + acc1.w) * n1);
    atomicAdd(&out[3*i+1], (acc2.x + acc2.y + acc2.z + acc2.w) * n2);
    atomicAdd(&out[3*i+2], (acc3.x + acc3.y + acc3.z + acc3.w) * n3);
}

extern "C" void kernel_launch(void* const* d_in, const int* in_sizes, int n_in,
                              void* d_out, int out_size, void* d_ws, size_t ws_size,
                              hipStream_t stream)
{
    const float* rho     = (const float*)d_in[0];
    const float* gamma   = (const float*)d_in[1];
    const float* coords  = (const float*)d_in[2];
    const float* weights = (const float*)d_in[3];
    float*       out     = (float*)d_out;
    const int    n       = in_sizes[0];

    const double C2d  = pow(6.0 * M_PI * M_PI, 2.0 / 3.0) * (6.0 * 2.0 / (160.0 * M_PI));
    const double Kd   = 0.3 * pow(3.0 * M_PI * M_PI, 2.0 / 3.0);
    const float  nrm1 = (float)pow(1.5, 1.5);
    const float  nrm2 = (float)pow(2.0, 1.5);
    const float  nrm3 = (float)pow(3.0, 1.5);

    // R2's proven workspace footprint: 6*n floats = 384 KB
    float* X  = (float*)d_ws;
    float* Y  = X  + n;
    float* Z  = Y  + n;
    float* Q  = Z  + n;
    float* An = Q  + n;
    float* F  = An + n;

    cider_pre<<<(n + 255) / 256, 256, 0, stream>>>(rho, gamma, coords, weights,
                                                   X, Y, Z, Q, An, F,
                                                   n, (float)C2d, (float)Kd);

    hipMemsetAsync(out, 0, (size_t)out_size * sizeof(float), stream);

    dim3 grid(n / BLOCK, SPLIT);
    cider_main<<<grid, BLOCK, 0, stream>>>(X, Y, Z, Q, An, F, out,
                                           n, 0, nrm1, nrm2, nrm3);
}

// Round 7
// 145.750 us; speedup vs baseline: 1.2765x; 1.2765x over previous
//
#include <hip/hip_runtime.h>
#include <math.h>

#ifndef M_PI
#define M_PI 3.14159265358979323846
#endif

constexpr int NCELLS = 16 * 16 * 16;  // Morton grid 16^3, cell side 2.0, world [-16,16)
constexpr int TSZ    = 64;            // points per tile (= wavefront)
constexpr int SPLIT  = 32;            // j-tile slices (blockIdx.y)

// y[i,c] = norms[c] * sum_j exp(-(a_j + b_ic) * ||xi-xj||^2) * f_j
// b[i,:] = {a_i/2, a_i, 2a_i}  (B0=B2, C0=C2 when A=D=2)
// u = exp2(-(Ai/2) s), A = exp2(-Aj s), A* = a*log2e  ->  w = {A u, A u^2, A u^4}
//
// Pruning: pair negligible when (Aj+Bi)*s >= 24 + log2(norms3*f_j); skipped-mass
// bound <= 16384 * norms3 * 2^-26.4 ~ 1e-3  << 6.2e-2 threshold.
// Spatial coherence via Morton counting sort; skip whole 64-j tiles per wave.

__device__ __forceinline__ int expand4(int v) {  // 4 bits -> every 3rd bit
    return (v & 1) | ((v & 2) << 2) | ((v & 4) << 4) | ((v & 8) << 6);
}

// K1: Morton cell id + histogram
__global__ __launch_bounds__(256)
void k_hist(const float* __restrict__ coords, int* __restrict__ cellid,
            int* __restrict__ hist, int n)
{
    int i = blockIdx.x * 256 + threadIdx.x;
    if (i >= n) return;
    float x = coords[3*i], y = coords[3*i+1], z = coords[3*i+2];
    int cx = min(15, max(0, (int)floorf((x + 16.f) * 0.5f)));
    int cy = min(15, max(0, (int)floorf((y + 16.f) * 0.5f)));
    int cz = min(15, max(0, (int)floorf((z + 16.f) * 0.5f)));
    int m = expand4(cx) | (expand4(cy) << 1) | (expand4(cz) << 2);
    cellid[i] = m;
    atomicAdd(&hist[m], 1);
}

// K2: exclusive scan hist -> cursor (one 1024-thread block, 4 cells/thread)
__global__ __launch_bounds__(1024)
void k_scan(const int* __restrict__ hist, int* __restrict__ cursor)
{
    __shared__ int sd[1024];
    int t = threadIdx.x;
    int h0 = hist[4*t], h1 = hist[4*t+1], h2 = hist[4*t+2], h3 = hist[4*t+3];
    int s = h0 + h1 + h2 + h3;
    sd[t] = s;
    __syncthreads();
    for (int off = 1; off < 1024; off <<= 1) {
        int v = (t >= off) ? sd[t - off] : 0;
        __syncthreads();
        sd[t] += v;
        __syncthreads();
    }
    int excl = sd[t] - s;
    cursor[4*t]   = excl;
    cursor[4*t+1] = excl + h0;
    cursor[4*t+2] = excl + h0 + h1;
    cursor[4*t+3] = excl + h0 + h1 + h2;
}

// K3: scatter into sorted order + per-point precompute
__global__ __launch_bounds__(256)
void k_scatter(const float* __restrict__ rho, const float* __restrict__ gamma,
               const float* __restrict__ coords, const float* __restrict__ weights,
               const int* __restrict__ cellid, int* __restrict__ cursor,
               float4* __restrict__ XYZA, float* __restrict__ Fs,
               int* __restrict__ perm, int n, float C2, float Kttf)
{
    int i = blockIdx.x * 256 + threadIdx.x;
    if (i >= n) return;
    int pos = atomicAdd(&cursor[cellid[i]], 1);
    const float LOG2E = 1.4426950408889634f;
    const float PI_F  = 3.14159265358979f;
    float r  = rho[i] + 1e-8f;
    float sc = PI_F * powf(0.5f * r, 2.0f / 3.0f);
    float xq = (gamma[i] / (8.0f * r)) / (Kttf * powf(r, 5.0f / 3.0f));
    float A  = LOG2E * sc * (2.0f + C2 * xq);     // a * log2(e) > 0
    XYZA[pos] = make_float4(coords[3*i], coords[3*i+1], coords[3*i+2], A);
    Fs[pos]   = weights[i] * rho[i];
    perm[pos] = i;
}

// K4: per-tile bounds {minx,miny,minz,maxx, maxy,maxz, Amin, Lmax}
__global__ __launch_bounds__(64)
void k_bounds(const float4* __restrict__ XYZA, const float* __restrict__ Fs,
              float* __restrict__ tiles)
{
    int p = blockIdx.x * TSZ + threadIdx.x;
    float4 v = XYZA[p];
    float lf = log2f(fmaxf(Fs[p], 1e-30f));
    float mnx=v.x, mny=v.y, mnz=v.z, mxx=v.x, mxy=v.y, mxz=v.z, mA=v.w, mL=lf;
    for (int d = 1; d < 64; d <<= 1) {
        mnx = fminf(mnx, __shfl_xor(mnx, d));
        mny = fminf(mny, __shfl_xor(mny, d));
        mnz = fminf(mnz, __shfl_xor(mnz, d));
        mxx = fmaxf(mxx, __shfl_xor(mxx, d));
        mxy = fmaxf(mxy, __shfl_xor(mxy, d));
        mxz = fmaxf(mxz, __shfl_xor(mxz, d));
        mA  = fminf(mA,  __shfl_xor(mA,  d));
        mL  = fmaxf(mL,  __shfl_xor(mL,  d));
    }
    if (threadIdx.x == 0) {
        float* tb = tiles + blockIdx.x * 8;
        tb[0]=mnx; tb[1]=mny; tb[2]=mnz; tb[3]=mxx;
        tb[4]=mxy; tb[5]=mxz; tb[6]=mA;  tb[7]=mL;
    }
}

// K5: main — per wave one i-tile; AABB-prune j-tiles; R2-style scalar inner loop
__global__ __launch_bounds__(256)
void k_main(const float4* __restrict__ XYZA, const float* __restrict__ Fs,
            const int* __restrict__ perm, const float* __restrict__ tiles,
            float* __restrict__ out, int nt,
            float n1, float n2, float n3)
{
    const int wave = threadIdx.x >> 6;
    const int lane = threadIdx.x & 63;
    const int it   = blockIdx.x * 4 + wave;      // i-tile index
    const int p    = it * TSZ + lane;

    float4 me = XYZA[p];
    const float xi = me.x, yi = me.y, zi = me.z;
    const float m2 = 0.5f * me.w;                // Bi = (a_i/2) * log2e

    // wave AABB + Bmin (butterfly -> all lanes hold result)
    float mnx=xi, mny=yi, mnz=zi, mxx=xi, mxy=yi, mxz=zi, mB=m2;
    for (int d = 1; d < 64; d <<= 1) {
        mnx = fminf(mnx, __shfl_xor(mnx, d));
        mny = fminf(mny, __shfl_xor(mny, d));
        mnz = fminf(mnz, __shfl_xor(mnz, d));
        mxx = fmaxf(mxx, __shfl_xor(mxx, d));
        mxy = fmaxf(mxy, __shfl_xor(mxy, d));
        mxz = fmaxf(mxz, __shfl_xor(mxz, d));
        mB  = fminf(mB,  __shfl_xor(mB,  d));
    }

    float acc1 = 0.f, acc2 = 0.f, acc3 = 0.f;
    bool any = false;

    const int tps = nt / SPLIT;                  // tiles per slice
    for (int k = 0; k < tps; ++k) {
        int jt = blockIdx.y * tps + k;
        const float* tb = tiles + jt * 8;
        float gx = fmaxf(0.f, fmaxf(tb[0] - mxx, mnx - tb[3]));
        float gy = fmaxf(0.f, fmaxf(tb[1] - mxy, mny - tb[4]));
        float gz = fmaxf(0.f, fmaxf(tb[2] - mxz, mnz - tb[5]));
        float d2 = gx*gx + gy*gy + gz*gz;
        float scut = (26.4f + tb[7]) / (tb[6] + mB);   // 24 + log2(norms3) + Lmax
        if (d2 > scut) continue;
        any = true;
        int jb = jt * TSZ;
        #pragma unroll 4
        for (int jj = 0; jj < TSZ; ++jj) {
            float4 J = XYZA[jb + jj];            // uniform addr -> s_load
            float fj = Fs[jb + jj];
            float dx = xi - J.x, dy = yi - J.y, dz = zi - J.z;
            float s  = fmaf(dx, dx, fmaf(dy, dy, dz * dz));
            float A  = __builtin_amdgcn_exp2f(-(J.w * s));
            float u  = __builtin_amdgcn_exp2f(-(m2 * s));
            float u2 = u * u, u4 = u2 * u2;
            float t0 = A * fj;
            acc1 = fmaf(t0, u,  acc1);
            acc2 = fmaf(t0, u2, acc2);
            acc3 = fmaf(t0, u4, acc3);
        }
    }

    if (any) {
        int orig = perm[p];
        atomicAdd(&out[3*orig+0], acc1 * n1);
        atomicAdd(&out[3*orig+1], acc2 * n2);
        atomicAdd(&out[3*orig+2], acc3 * n3);
    }
}

extern "C" void kernel_launch(void* const* d_in, const int* in_sizes, int n_in,
                              void* d_out, int out_size, void* d_ws, size_t ws_size,
                              hipStream_t stream)
{
    const float* rho     = (const float*)d_in[0];
    const float* gamma   = (const float*)d_in[1];
    const float* coords  = (const float*)d_in[2];
    const float* weights = (const float*)d_in[3];
    float*       out     = (float*)d_out;
    const int    n       = in_sizes[0];
    const int    nt      = n / TSZ;              // 256 tiles

    const double C2d  = pow(6.0 * M_PI * M_PI, 2.0 / 3.0) * (6.0 * 2.0 / (160.0 * M_PI));
    const double Kd   = 0.3 * pow(3.0 * M_PI * M_PI, 2.0 / 3.0);
    const float  nrm1 = (float)pow(1.5, 1.5);
    const float  nrm2 = (float)pow(2.0, 1.5);
    const float  nrm3 = (float)pow(3.0, 1.5);

    // workspace layout (~500 KB for n=16384)
    char* w = (char*)d_ws;
    float4* XYZA   = (float4*)w;                 w += (size_t)n * sizeof(float4);
    float*  Fs     = (float*)w;                  w += (size_t)n * sizeof(float);
    int*    perm   = (int*)w;                    w += (size_t)n * sizeof(int);
    int*    cellid = (int*)w;                    w += (size_t)n * sizeof(int);
    int*    hist   = (int*)w;                    w += (size_t)NCELLS * sizeof(int);
    int*    cursor = (int*)w;                    w += (size_t)NCELLS * sizeof(int);
    float*  tiles  = (float*)w;                  w += (size_t)nt * 8 * sizeof(float);

    hipMemsetAsync(hist, 0, NCELLS * sizeof(int), stream);
    hipMemsetAsync(out, 0, (size_t)out_size * sizeof(float), stream);

    k_hist   <<<(n + 255) / 256, 256, 0, stream>>>(coords, cellid, hist, n);
    k_scan   <<<1, 1024, 0, stream>>>(hist, cursor);
    k_scatter<<<(n + 255) / 256, 256, 0, stream>>>(rho, gamma, coords, weights,
                                                   cellid, cursor, XYZA, Fs, perm,
                                                   n, (float)C2d, (float)Kd);
    k_bounds <<<nt, TSZ, 0, stream>>>(XYZA, Fs, tiles);

    dim3 grid(nt / 4, SPLIT);
    k_main   <<<grid, 256, 0, stream>>>(XYZA, Fs, perm, tiles, out, nt,
                                        nrm1, nrm2, nrm3);
}